// Round 9
// baseline (4551.941 us; speedup 1.0000x reference)
//
#include <hip/hip_runtime.h>

// LSTM stack: B=64, T=256, N=M=1024, L=2.
// Persistent cooperative kernel: 256 WGs (1/CU), 1024 threads (16 waves).
// Mat-paired wave groups (dedup h0 reads):
//   group A (waves 0-7):  reads h0 once -> MFMA Wh0 (l0 acc0) + Wx1 (l1 acc1)
//   group B (waves 8-15): reads x + h1 -> Wx0 (acc0) + Wh1 (acc1)
// h state in 32-slot RING buffers (fresh address per step => no stale caches,
// no invalidates except a leader L2-inv every 32 steps at ring wrap).
// h stores: relaxed agent atomic stores (write-through to LLC).
// BARRIER (new, RMW-free): arrival = tid0 stores flags[cu]=k+1 (sc0 sc1,
// after vmcnt drain of h stores); release = wave 0 of EVERY WG reads all 256
// flags in ONE global_load_dwordx4 sc0 sc1 (64 lanes x 16B) and ballots
// all >= target. No atomics, no tree, no leader hop on normal steps.

#define T_STEPS 256
#define B_SZ 64
#define M_SZ 1024
#define N_SZ 1024
#define G4M 4096
#define BM 65536                       // B*M
#define RING 32
#define OUTS ((size_t)16777216)        // B*T*M

typedef short short8 __attribute__((ext_vector_type(8)));
typedef float f32x4 __attribute__((ext_vector_type(4)));
typedef int i32x4 __attribute__((ext_vector_type(4)));

static __device__ __forceinline__ unsigned short f2bf(float f) {
  union { float f; unsigned int u; } v; v.f = f;
  unsigned int u = v.u;
  unsigned int r = (u + 0x7FFFu + ((u >> 16) & 1u)) >> 16;
  return (unsigned short)r;
}

static __device__ __forceinline__ float sigf(float x) {
  return 1.f / (1.f + __expf(-x));
}
static __device__ __forceinline__ float tanhfast(float x) {
  return 2.f / (1.f + __expf(-2.f * x)) - 1.f;
}

static __device__ __forceinline__ short8 ld16(const unsigned short* p) {
  return *reinterpret_cast<const short8*>(p);
}

// write-through 16B store (out buffer only; never re-read on device)
static __device__ __forceinline__ void store_wt16(void* p, f32x4 v) {
  asm volatile("global_store_dwordx4 %0, %1, off sc0 sc1" :: "v"(p), "v"(v) : "memory");
}

static __device__ __forceinline__ int xcc_id() {
  int v;
  asm volatile("s_getreg_b32 %0, hwreg(HW_REG_XCC_ID)" : "=s"(v));
  return v & 7;
}

__global__ void convert_x_kernel(const float* __restrict__ x,
                                 unsigned short* __restrict__ xb, int n4) {
  int i = blockIdx.x * blockDim.x + threadIdx.x;
  int stride = gridDim.x * blockDim.x;
  for (; i < n4; i += stride) {
    float4 v = reinterpret_cast<const float4*>(x)[i];
    ushort4 o;
    o.x = f2bf(v.x); o.y = f2bf(v.y); o.z = f2bf(v.z); o.w = f2bf(v.w);
    reinterpret_cast<ushort4*>(xb)[i] = o;
  }
}

__global__ void init_h_kernel(const float* __restrict__ h,
                              unsigned short* __restrict__ h0r,
                              unsigned short* __restrict__ h1r) {
  int i = blockIdx.x * blockDim.x + threadIdx.x;  // 0..65535
  h0r[(size_t)(RING - 1) * BM + i] = f2bf(h[i]);      // layer0 reads slot 31 at k=0
  h1r[i]                           = f2bf(h[BM + i]); // layer1 reads slot 0 at k=1
}

// bar layout (ints): flags[0..255]; relB[xcd] at 256+16*xcd; claim[xcd] at 512+16*xcd
__global__ __launch_bounds__(1024, 4) void lstm_persistent(
    const unsigned short* __restrict__ xb,   // [B][T][N] bf16 (cached)
    const float* __restrict__ c_in,          // [L][B][M]
    const float* __restrict__ Wx,            // [L][4M][N]
    const float* __restrict__ Wh,            // [L][4M][M]
    const float* __restrict__ bias,          // [L][4M]
    float* __restrict__ out,                 // outs | h_last | c_last
    unsigned short* __restrict__ h0r,        // [RING][B][M] bf16
    unsigned short* __restrict__ h1r,        // [RING][B][M] bf16
    int* bar) {
  __shared__ short8 sW[4][32][64];   // 128 KiB fragment-packed weights
  __shared__ f32x4 red1[12][64];     // 12 KiB l0 partials
  __shared__ f32x4 red2[12][64];     // 12 KiB l1 partials

  const int cu = blockIdx.x;
  const int tid = threadIdx.x;
  const int lane = tid & 63;
  const int w = tid >> 6;        // 0..15
  const bool grpA = (w < 8);
  const int kh = (w >> 2) & 1;   // k-half
  const int bt = w & 3;          // batch tile
  const int q = lane >> 4;
  const int bl = lane & 15;
  const int bg = bt * 16 + bl;
  const int m0 = cu * 4;
  const int xcd = xcc_id();
  int* flags = bar;

  // ---- stage weights (once) ----
  const float* gbase[4] = { Wx, Wh, Wx + (size_t)G4M * N_SZ, Wh + (size_t)G4M * M_SZ };
  for (int mat = 0; mat < 4; ++mat) {
    const float* base = gbase[mat];
    for (int s = tid; s < 32 * 64; s += 1024) {
      int kt = s >> 6, ls = s & 63;
      int r = ls & 15;
      int k0 = kt * 32 + (ls >> 4) * 8;
      int j = (r >> 2) * 1024 + m0 + (r & 3);
      const float* src = base + (size_t)j * 1024 + k0;
      float4 a = reinterpret_cast<const float4*>(src)[0];
      float4 b2 = reinterpret_cast<const float4*>(src)[1];
      short8 wv;
      wv[0] = (short)f2bf(a.x); wv[1] = (short)f2bf(a.y);
      wv[2] = (short)f2bf(a.z); wv[3] = (short)f2bf(a.w);
      wv[4] = (short)f2bf(b2.x); wv[5] = (short)f2bf(b2.y);
      wv[6] = (short)f2bf(b2.z); wv[7] = (short)f2bf(b2.w);
      sW[mat][kt][ls] = wv;
    }
  }

  // ---- static per-XCD leader election (once) ----
  bool leader = false;
  if (tid == 0) {
    int expected = 0;
    leader = __hip_atomic_compare_exchange_strong(
        bar + 512 + 16 * xcd, &expected, cu + 1, __ATOMIC_RELAXED,
        __ATOMIC_RELAXED, __HIP_MEMORY_SCOPE_AGENT);
  }
  __syncthreads();

  // ---- pointwise-owner state ----
  float c_st[4] = {0.f, 0.f, 0.f, 0.f};
  float bs[4] = {0.f, 0.f, 0.f, 0.f};
  if (kh == 0) {
    const int layer = grpA ? 0 : 1;
#pragma unroll
    for (int e = 0; e < 4; ++e) {
      c_st[e] = c_in[layer * BM + bg * M_SZ + m0 + e];
      bs[e] = bias[layer * G4M + q * 1024 + m0 + e];
    }
  }

  const int ko = q * 8;
  const int ktb = kh * 16;

  for (int k = 0; k <= T_STEPS; ++k) {
    const int rs = (k + RING - 1) & (RING - 1);  // read slot (state from k-1)
    const int wslot = k & (RING - 1);            // write slot
    f32x4 acc0 = { 0.f, 0.f, 0.f, 0.f };   // l0-product partial
    f32x4 acc1 = { 0.f, 0.f, 0.f, 0.f };   // l1-product partial
    if (kh == 0) {
      if (grpA) { acc0[0] = bs[0]; acc0[1] = bs[1]; acc0[2] = bs[2]; acc0[3] = bs[3]; }
      else      { acc1[0] = bs[0]; acc1[1] = bs[1]; acc1[2] = bs[2]; acc1[3] = bs[3]; }
    }

    if (grpA) {
      // ---- A: read h0 once (16 loads in flight); Wh0->acc0, Wx1->acc1 ----
      const unsigned short* ph0 = h0r + (size_t)rs * BM + (size_t)bg * M_SZ;
      short8 a[16];
#pragma unroll
      for (int j = 0; j < 16; ++j) a[j] = ld16(ph0 + (ktb + j) * 32 + ko);
      __builtin_amdgcn_sched_barrier(0);
#pragma unroll
      for (int j = 0; j < 16; ++j) {
        int kt = ktb + j;
        acc0 = __builtin_amdgcn_mfma_f32_16x16x32_bf16(sW[1][kt][lane], a[j], acc0, 0, 0, 0);
        acc1 = __builtin_amdgcn_mfma_f32_16x16x32_bf16(sW[2][kt][lane], a[j], acc1, 0, 0, 0);
      }
    } else {
      // ---- B: 16 h1 + 8 x loads in flight; Wx0->acc0, Wh1->acc1 ----
      const int tl0 = (k < T_STEPS) ? k : (T_STEPS - 1);
      const unsigned short* px = xb + ((size_t)bg * T_STEPS + tl0) * N_SZ;
      const unsigned short* ph1 = h1r + (size_t)rs * BM + (size_t)bg * M_SZ;
      short8 fh[16], xa[8];
#pragma unroll
      for (int j = 0; j < 16; ++j) fh[j] = ld16(ph1 + (ktb + j) * 32 + ko);
#pragma unroll
      for (int j = 0; j < 8; ++j) xa[j] = ld16(px + (ktb + j) * 32 + ko);
      __builtin_amdgcn_sched_barrier(0);
#pragma unroll
      for (int j = 0; j < 8; ++j) {
        int kt = ktb + j;
        acc0 = __builtin_amdgcn_mfma_f32_16x16x32_bf16(sW[0][kt][lane], xa[j], acc0, 0, 0, 0);
        acc1 = __builtin_amdgcn_mfma_f32_16x16x32_bf16(sW[3][kt][lane], fh[j], acc1, 0, 0, 0);
      }
      short8 xc[8];
#pragma unroll
      for (int j = 0; j < 8; ++j) xc[j] = ld16(px + (ktb + 8 + j) * 32 + ko);
#pragma unroll
      for (int j = 0; j < 8; ++j) {
        int kt = ktb + 8 + j;
        acc0 = __builtin_amdgcn_mfma_f32_16x16x32_bf16(sW[0][kt][lane], xc[j], acc0, 0, 0, 0);
        acc1 = __builtin_amdgcn_mfma_f32_16x16x32_bf16(sW[3][kt][lane], fh[8 + j], acc1, 0, 0, 0);
      }
    }

    // ---- partial-sum exchange (LDS-only sync) ----
    if (w < 4)            { red2[bt][lane] = acc1; }
    else if (w < 8)       { red1[bt][lane] = acc0; red2[4 + bt][lane] = acc1; }
    else if (w < 12)      { red1[4 + bt][lane] = acc0; }
    else                  { red1[8 + bt][lane] = acc0; red2[8 + bt][lane] = acc1; }
    asm volatile("s_waitcnt lgkmcnt(0)" ::: "memory");
    __builtin_amdgcn_s_barrier();
    __builtin_amdgcn_sched_barrier(0);

    // ---- layer-0 pointwise (waves 0..3), t = k ----
    if (w < 4 && k < T_STEPS) {
      f32x4 tot = acc0 + red1[bt][lane] + red1[4 + bt][lane] + red1[8 + bt][lane];
      float hv[4];
#pragma unroll
      for (int e = 0; e < 4; ++e) {
        float ge_i = __shfl(tot[e], bl);
        float ge_f = __shfl(tot[e], bl + 16);
        float ge_g = __shfl(tot[e], bl + 32);
        float ge_o = __shfl(tot[e], bl + 48);
        float gi = sigf(ge_i), gf = sigf(ge_f);
        float gg = tanhfast(ge_g), go = sigf(ge_o);
        float c = gf * c_st[e] + gi * gg;
        c_st[e] = c;
        hv[e] = go * tanhfast(c);
      }
      if (q == 0) {
        unsigned short* hdst = h0r + (size_t)wslot * BM + (size_t)bg * M_SZ + m0;
        unsigned long long hb =
            (unsigned long long)f2bf(hv[0]) |
            ((unsigned long long)f2bf(hv[1]) << 16) |
            ((unsigned long long)f2bf(hv[2]) << 32) |
            ((unsigned long long)f2bf(hv[3]) << 48);
        __hip_atomic_store((unsigned long long*)hdst, hb, __ATOMIC_RELAXED,
                           __HIP_MEMORY_SCOPE_AGENT);
        if (k == T_STEPS - 1) {
          f32x4 hf = { hv[0], hv[1], hv[2], hv[3] };
          f32x4 cf = { c_st[0], c_st[1], c_st[2], c_st[3] };
          store_wt16(out + OUTS + (size_t)bg * M_SZ + m0, hf);
          store_wt16(out + OUTS + 2 * (size_t)BM + (size_t)bg * M_SZ + m0, cf);
        }
      }
    }

    // ---- layer-1 pointwise (waves 8..11), t = k-1 ----
    if (w >= 8 && w < 12 && k >= 1) {
      const int t = k - 1;
      f32x4 tot = acc1 + red2[bt][lane] + red2[4 + bt][lane] + red2[8 + bt][lane];
      float hv[4];
#pragma unroll
      for (int e = 0; e < 4; ++e) {
        float ge_i = __shfl(tot[e], bl);
        float ge_f = __shfl(tot[e], bl + 16);
        float ge_g = __shfl(tot[e], bl + 32);
        float ge_o = __shfl(tot[e], bl + 48);
        float gi = sigf(ge_i), gf = sigf(ge_f);
        float gg = tanhfast(ge_g), go = sigf(ge_o);
        float c = gf * c_st[e] + gi * gg;
        c_st[e] = c;
        hv[e] = go * tanhfast(c);
      }
      if (q == 0) {
        unsigned short* hdst = h1r + (size_t)wslot * BM + (size_t)bg * M_SZ + m0;
        unsigned long long hb =
            (unsigned long long)f2bf(hv[0]) |
            ((unsigned long long)f2bf(hv[1]) << 16) |
            ((unsigned long long)f2bf(hv[2]) << 32) |
            ((unsigned long long)f2bf(hv[3]) << 48);
        __hip_atomic_store((unsigned long long*)hdst, hb, __ATOMIC_RELAXED,
                           __HIP_MEMORY_SCOPE_AGENT);
        f32x4 ov = { hv[0], hv[1], hv[2], hv[3] };
        store_wt16(out + ((size_t)bg * T_STEPS + t) * M_SZ + m0, ov);
        if (k == T_STEPS) {
          f32x4 hf = { hv[0], hv[1], hv[2], hv[3] };
          f32x4 cf = { c_st[0], c_st[1], c_st[2], c_st[3] };
          store_wt16(out + OUTS + (size_t)BM + (size_t)bg * M_SZ + m0, hf);
          store_wt16(out + OUTS + 3 * (size_t)BM + (size_t)bg * M_SZ + m0, cf);
        }
      }
    }

    // ---- grid barrier: flag store + lane-parallel flag poll (no RMWs) ----
    if (k < T_STEPS) {
      const int target = k + 1;
      const bool invstep = ((k & (RING - 1)) == (RING - 1));
      if (w < 4 || (w >= 8 && w < 12))
        asm volatile("s_waitcnt vmcnt(0)" ::: "memory");
      __builtin_amdgcn_s_barrier();          // all h stores visible at LLC
      if (w == 0) {
        if (lane == 0) {
          // arrival: one write-through dword, no RMW
          asm volatile("global_store_dword %0, %1, off sc0 sc1"
                       :: "v"(flags + cu), "v"(target) : "memory");
        }
        // release: 64 lanes x dwordx4 = all 256 flags in one instruction
        const int* fp = flags + lane * 4;
        int guard = 0;
        for (;;) {
          i32x4 v;
          asm volatile("global_load_dwordx4 %0, %1, off sc0 sc1\n\ts_waitcnt vmcnt(0)"
                       : "=v"(v) : "v"(fp) : "memory");
          int ok = (v[0] >= target) && (v[1] >= target) &&
                   (v[2] >= target) && (v[3] >= target);
          if (__all(ok)) break;
          __builtin_amdgcn_s_sleep(2);
          if (++guard > (1 << 16)) break;    // failsafe: wrong answer, not hang
        }
      }
      __builtin_amdgcn_s_barrier();          // release to all 16 waves
      if (invstep) {                         // ring wrap: drop stale L1/L2 lines
        if (tid == 0) {
          int* relB = bar + 256 + 16 * xcd;
          if (leader) {
            asm volatile("buffer_inv sc0 sc1\n\ts_waitcnt vmcnt(0)" ::: "memory");
            __hip_atomic_store(relB, target, __ATOMIC_RELAXED, __HIP_MEMORY_SCOPE_AGENT);
          } else {
            int guard = 0;
            while (__hip_atomic_load(relB, __ATOMIC_RELAXED, __HIP_MEMORY_SCOPE_AGENT) < target) {
              __builtin_amdgcn_s_sleep(2);
              if (++guard > (1 << 18)) break;
            }
            asm volatile("buffer_inv sc0\n\ts_waitcnt vmcnt(0)" ::: "memory");
          }
        }
        __builtin_amdgcn_s_barrier();
      }
      __builtin_amdgcn_sched_barrier(0);     // keep next-step h loads below
    }
  }
}

extern "C" void kernel_launch(void* const* d_in, const int* in_sizes, int n_in,
                              void* d_out, int out_size, void* d_ws, size_t ws_size,
                              hipStream_t stream) {
  (void)in_sizes; (void)n_in; (void)out_size; (void)ws_size;
  const float* x  = (const float*)d_in[0];
  const float* h  = (const float*)d_in[1];
  const float* c  = (const float*)d_in[2];
  const float* Wx = (const float*)d_in[3];
  const float* Wh = (const float*)d_in[4];
  const float* b  = (const float*)d_in[5];
  float* out = (float*)d_out;

  char* ws = (char*)d_ws;
  int* bar = (int*)ws;                              // flags + relB + claim
  unsigned short* h0r = (unsigned short*)(ws + 4096);
  unsigned short* h1r = (unsigned short*)(ws + 4096 + (size_t)RING * BM * 2);
  unsigned short* xb  = (unsigned short*)(ws + 4096 + (size_t)RING * BM * 4);
  // ws use: 4096 + 2*4MB (h rings) + 32MB (xb) ~= 40 MB

  (void)hipMemsetAsync(ws, 0, 4096, stream);
  convert_x_kernel<<<2048, 256, 0, stream>>>(x, xb, (B_SZ * T_STEPS * N_SZ) / 4);
  init_h_kernel<<<256, 256, 0, stream>>>(h, h0r, h1r);
  lstm_persistent<<<256, 1024, 0, stream>>>(xb, c, Wx, Wh, b, out, h0r, h1r, bar);
}

// Round 10
// 3927.931 us; speedup vs baseline: 1.1589x; 1.1589x over previous
//
#include <hip/hip_runtime.h>

// LSTM stack: B=64, T=256, N=M=1024, L=2.
// Persistent cooperative kernel: 256 WGs (1/CU), 1024 threads (16 waves).
// Mat-paired wave groups (dedup h0 reads):
//   group A (waves 0-7):  reads h0 once -> MFMA Wh0 (l0 acc0) + Wx1 (l1 acc1)
//   group B (waves 8-15): reads x + h1 -> Wx0 (acc0) + Wh1 (acc1)
// h state in 32-slot RING buffers (fresh address per step => no stale caches;
// leader L2-inv only at ring wrap, every 32 steps).
// h stores: relaxed agent atomic stores (write-through to LLC).
// Barrier: 32-leaf tree (8 WGs/leaf) -> root; last root arriver broadcasts 8
// per-XCD release lines; pollers poll their XCD line only.
// NEW: keep-alive asm forces ALL per-step fragment loads simultaneously live
// (one LLC round trip, VGPR ~120); waves 8-11 drain only to vmcnt(1) so the
// HBM out-store doesn't sit on the barrier critical path.

#define T_STEPS 256
#define B_SZ 64
#define M_SZ 1024
#define N_SZ 1024
#define G4M 4096
#define BM 65536                       // B*M
#define RING 32
#define OUTS ((size_t)16777216)        // B*T*M

typedef short short8 __attribute__((ext_vector_type(8)));
typedef float f32x4 __attribute__((ext_vector_type(4)));

static __device__ __forceinline__ unsigned short f2bf(float f) {
  union { float f; unsigned int u; } v; v.f = f;
  unsigned int u = v.u;
  unsigned int r = (u + 0x7FFFu + ((u >> 16) & 1u)) >> 16;
  return (unsigned short)r;
}

static __device__ __forceinline__ float sigf(float x) {
  return 1.f / (1.f + __expf(-x));
}
static __device__ __forceinline__ float tanhfast(float x) {
  return 2.f / (1.f + __expf(-2.f * x)) - 1.f;
}

static __device__ __forceinline__ short8 ld16(const unsigned short* p) {
  return *reinterpret_cast<const short8*>(p);
}

// write-through 16B store (out buffer only; never re-read on device)
static __device__ __forceinline__ void store_wt16(void* p, f32x4 v) {
  asm volatile("global_store_dwordx4 %0, %1, off sc0 sc1" :: "v"(p), "v"(v) : "memory");
}

static __device__ __forceinline__ int xcc_id() {
  int v;
  asm volatile("s_getreg_b32 %0, hwreg(HW_REG_XCC_ID)" : "=s"(v));
  return v & 7;
}

__global__ void convert_x_kernel(const float* __restrict__ x,
                                 unsigned short* __restrict__ xb, int n4) {
  int i = blockIdx.x * blockDim.x + threadIdx.x;
  int stride = gridDim.x * blockDim.x;
  for (; i < n4; i += stride) {
    float4 v = reinterpret_cast<const float4*>(x)[i];
    ushort4 o;
    o.x = f2bf(v.x); o.y = f2bf(v.y); o.z = f2bf(v.z); o.w = f2bf(v.w);
    reinterpret_cast<ushort4*>(xb)[i] = o;
  }
}

__global__ void init_h_kernel(const float* __restrict__ h,
                              unsigned short* __restrict__ h0r,
                              unsigned short* __restrict__ h1r) {
  int i = blockIdx.x * blockDim.x + threadIdx.x;  // 0..65535
  h0r[(size_t)(RING - 1) * BM + i] = f2bf(h[i]);      // layer0 reads slot 31 at k=0
  h1r[i]                           = f2bf(h[BM + i]); // layer1 reads slot 0 at k=1
}

// bar slots (64B each): leaf[0..31]=0-31, root=32, rel[xcd]=34+x,
// relB[xcd]=42+x, claim[xcd]=50+x
__global__ __launch_bounds__(1024, 4) void lstm_persistent(
    const unsigned short* __restrict__ xb,   // [B][T][N] bf16 (cached)
    const float* __restrict__ c_in,          // [L][B][M]
    const float* __restrict__ Wx,            // [L][4M][N]
    const float* __restrict__ Wh,            // [L][4M][M]
    const float* __restrict__ bias,          // [L][4M]
    float* __restrict__ out,                 // outs | h_last | c_last
    unsigned short* __restrict__ h0r,        // [RING][B][M] bf16
    unsigned short* __restrict__ h1r,        // [RING][B][M] bf16
    int* bar) {
  __shared__ short8 sW[4][32][64];   // 128 KiB fragment-packed weights
  __shared__ f32x4 red1[12][64];     // 12 KiB l0 partials
  __shared__ f32x4 red2[12][64];     // 12 KiB l1 partials

  const int cu = blockIdx.x;
  const int tid = threadIdx.x;
  const int lane = tid & 63;
  const int w = tid >> 6;        // 0..15
  const bool grpA = (w < 8);
  const int kh = (w >> 2) & 1;   // k-half
  const int bt = w & 3;          // batch tile
  const int q = lane >> 4;
  const int bl = lane & 15;
  const int bg = bt * 16 + bl;
  const int m0 = cu * 4;
  const int xcd = xcc_id();

  // ---- stage weights (once) ----
  const float* gbase[4] = { Wx, Wh, Wx + (size_t)G4M * N_SZ, Wh + (size_t)G4M * M_SZ };
  for (int mat = 0; mat < 4; ++mat) {
    const float* base = gbase[mat];
    for (int s = tid; s < 32 * 64; s += 1024) {
      int kt = s >> 6, ls = s & 63;
      int r = ls & 15;
      int k0 = kt * 32 + (ls >> 4) * 8;
      int j = (r >> 2) * 1024 + m0 + (r & 3);
      const float* src = base + (size_t)j * 1024 + k0;
      float4 a = reinterpret_cast<const float4*>(src)[0];
      float4 b2 = reinterpret_cast<const float4*>(src)[1];
      short8 wv;
      wv[0] = (short)f2bf(a.x); wv[1] = (short)f2bf(a.y);
      wv[2] = (short)f2bf(a.z); wv[3] = (short)f2bf(a.w);
      wv[4] = (short)f2bf(b2.x); wv[5] = (short)f2bf(b2.y);
      wv[6] = (short)f2bf(b2.z); wv[7] = (short)f2bf(b2.w);
      sW[mat][kt][ls] = wv;
    }
  }

  // ---- static per-XCD leader election (once) ----
  bool leader = false;
  if (tid == 0) {
    int expected = 0;
    leader = __hip_atomic_compare_exchange_strong(
        bar + 16 * (50 + xcd), &expected, cu + 1, __ATOMIC_RELAXED,
        __ATOMIC_RELAXED, __HIP_MEMORY_SCOPE_AGENT);
  }
  __syncthreads();

  // ---- pointwise-owner state ----
  float c_st[4] = {0.f, 0.f, 0.f, 0.f};
  float bs[4] = {0.f, 0.f, 0.f, 0.f};
  if (kh == 0) {
    const int layer = grpA ? 0 : 1;
#pragma unroll
    for (int e = 0; e < 4; ++e) {
      c_st[e] = c_in[layer * BM + bg * M_SZ + m0 + e];
      bs[e] = bias[layer * G4M + q * 1024 + m0 + e];
    }
  }

  const int ko = q * 8;
  const int ktb = kh * 16;

  for (int k = 0; k <= T_STEPS; ++k) {
    const int rs = (k + RING - 1) & (RING - 1);  // read slot (state from k-1)
    const int wslot = k & (RING - 1);            // write slot
    f32x4 acc0 = { 0.f, 0.f, 0.f, 0.f };   // l0-product partial
    f32x4 acc1 = { 0.f, 0.f, 0.f, 0.f };   // l1-product partial
    if (kh == 0) {
      if (grpA) { acc0[0] = bs[0]; acc0[1] = bs[1]; acc0[2] = bs[2]; acc0[3] = bs[3]; }
      else      { acc1[0] = bs[0]; acc1[1] = bs[1]; acc1[2] = bs[2]; acc1[3] = bs[3]; }
    }

    if (grpA) {
      // ---- A: read h0 once, ALL 16 loads live at once; Wh0->acc0, Wx1->acc1 ----
      const unsigned short* ph0 = h0r + (size_t)rs * BM + (size_t)bg * M_SZ;
      short8 a[16];
#pragma unroll
      for (int j = 0; j < 16; ++j) a[j] = ld16(ph0 + (ktb + j) * 32 + ko);
      asm volatile("" ::
        "v"(a[0]), "v"(a[1]), "v"(a[2]), "v"(a[3]),
        "v"(a[4]), "v"(a[5]), "v"(a[6]), "v"(a[7]),
        "v"(a[8]), "v"(a[9]), "v"(a[10]), "v"(a[11]),
        "v"(a[12]), "v"(a[13]), "v"(a[14]), "v"(a[15]));
      __builtin_amdgcn_sched_barrier(0);
#pragma unroll
      for (int j = 0; j < 16; ++j) {
        int kt = ktb + j;
        acc0 = __builtin_amdgcn_mfma_f32_16x16x32_bf16(sW[1][kt][lane], a[j], acc0, 0, 0, 0);
        acc1 = __builtin_amdgcn_mfma_f32_16x16x32_bf16(sW[2][kt][lane], a[j], acc1, 0, 0, 0);
      }
    } else {
      // ---- B: 16 h1 + 8 x loads, ALL live at once; Wx0->acc0, Wh1->acc1 ----
      const int tl0 = (k < T_STEPS) ? k : (T_STEPS - 1);
      const unsigned short* px = xb + ((size_t)bg * T_STEPS + tl0) * N_SZ;
      const unsigned short* ph1 = h1r + (size_t)rs * BM + (size_t)bg * M_SZ;
      short8 fh[16], xa[8];
#pragma unroll
      for (int j = 0; j < 16; ++j) fh[j] = ld16(ph1 + (ktb + j) * 32 + ko);
#pragma unroll
      for (int j = 0; j < 8; ++j) xa[j] = ld16(px + (ktb + j) * 32 + ko);
      asm volatile("" ::
        "v"(fh[0]), "v"(fh[1]), "v"(fh[2]), "v"(fh[3]),
        "v"(fh[4]), "v"(fh[5]), "v"(fh[6]), "v"(fh[7]),
        "v"(fh[8]), "v"(fh[9]), "v"(fh[10]), "v"(fh[11]),
        "v"(fh[12]), "v"(fh[13]), "v"(fh[14]), "v"(fh[15]),
        "v"(xa[0]), "v"(xa[1]), "v"(xa[2]), "v"(xa[3]),
        "v"(xa[4]), "v"(xa[5]), "v"(xa[6]), "v"(xa[7]));
      __builtin_amdgcn_sched_barrier(0);
#pragma unroll
      for (int j = 0; j < 8; ++j) {
        int kt = ktb + j;
        acc0 = __builtin_amdgcn_mfma_f32_16x16x32_bf16(sW[0][kt][lane], xa[j], acc0, 0, 0, 0);
        acc1 = __builtin_amdgcn_mfma_f32_16x16x32_bf16(sW[3][kt][lane], fh[j], acc1, 0, 0, 0);
      }
      short8 xc[8];
#pragma unroll
      for (int j = 0; j < 8; ++j) xc[j] = ld16(px + (ktb + 8 + j) * 32 + ko);
#pragma unroll
      for (int j = 0; j < 8; ++j) {
        int kt = ktb + 8 + j;
        acc0 = __builtin_amdgcn_mfma_f32_16x16x32_bf16(sW[0][kt][lane], xc[j], acc0, 0, 0, 0);
        acc1 = __builtin_amdgcn_mfma_f32_16x16x32_bf16(sW[3][kt][lane], fh[8 + j], acc1, 0, 0, 0);
      }
    }

    // ---- partial-sum exchange (LDS-only sync) ----
    if (w < 4)            { red2[bt][lane] = acc1; }
    else if (w < 8)       { red1[bt][lane] = acc0; red2[4 + bt][lane] = acc1; }
    else if (w < 12)      { red1[4 + bt][lane] = acc0; }
    else                  { red1[8 + bt][lane] = acc0; red2[8 + bt][lane] = acc1; }
    asm volatile("s_waitcnt lgkmcnt(0)" ::: "memory");
    __builtin_amdgcn_s_barrier();
    __builtin_amdgcn_sched_barrier(0);

    // ---- layer-0 pointwise (waves 0..3), t = k ----
    if (w < 4 && k < T_STEPS) {
      f32x4 tot = acc0 + red1[bt][lane] + red1[4 + bt][lane] + red1[8 + bt][lane];
      float hv[4];
#pragma unroll
      for (int e = 0; e < 4; ++e) {
        float ge_i = __shfl(tot[e], bl);
        float ge_f = __shfl(tot[e], bl + 16);
        float ge_g = __shfl(tot[e], bl + 32);
        float ge_o = __shfl(tot[e], bl + 48);
        float gi = sigf(ge_i), gf = sigf(ge_f);
        float gg = tanhfast(ge_g), go = sigf(ge_o);
        float c = gf * c_st[e] + gi * gg;
        c_st[e] = c;
        hv[e] = go * tanhfast(c);
      }
      if (q == 0) {
        unsigned short* hdst = h0r + (size_t)wslot * BM + (size_t)bg * M_SZ + m0;
        unsigned long long hb =
            (unsigned long long)f2bf(hv[0]) |
            ((unsigned long long)f2bf(hv[1]) << 16) |
            ((unsigned long long)f2bf(hv[2]) << 32) |
            ((unsigned long long)f2bf(hv[3]) << 48);
        __hip_atomic_store((unsigned long long*)hdst, hb, __ATOMIC_RELAXED,
                           __HIP_MEMORY_SCOPE_AGENT);
        if (k == T_STEPS - 1) {
          f32x4 hf = { hv[0], hv[1], hv[2], hv[3] };
          f32x4 cf = { c_st[0], c_st[1], c_st[2], c_st[3] };
          store_wt16(out + OUTS + (size_t)bg * M_SZ + m0, hf);
          store_wt16(out + OUTS + 2 * (size_t)BM + (size_t)bg * M_SZ + m0, cf);
        }
      }
    }

    // ---- layer-1 pointwise (waves 8..11), t = k-1 ----
    if (w >= 8 && w < 12 && k >= 1) {
      const int t = k - 1;
      f32x4 tot = acc1 + red2[bt][lane] + red2[4 + bt][lane] + red2[8 + bt][lane];
      float hv[4];
#pragma unroll
      for (int e = 0; e < 4; ++e) {
        float ge_i = __shfl(tot[e], bl);
        float ge_f = __shfl(tot[e], bl + 16);
        float ge_g = __shfl(tot[e], bl + 32);
        float ge_o = __shfl(tot[e], bl + 48);
        float gi = sigf(ge_i), gf = sigf(ge_f);
        float gg = tanhfast(ge_g), go = sigf(ge_o);
        float c = gf * c_st[e] + gi * gg;
        c_st[e] = c;
        hv[e] = go * tanhfast(c);
      }
      if (q == 0) {
        unsigned short* hdst = h1r + (size_t)wslot * BM + (size_t)bg * M_SZ + m0;
        unsigned long long hb =
            (unsigned long long)f2bf(hv[0]) |
            ((unsigned long long)f2bf(hv[1]) << 16) |
            ((unsigned long long)f2bf(hv[2]) << 32) |
            ((unsigned long long)f2bf(hv[3]) << 48);
        __hip_atomic_store((unsigned long long*)hdst, hb, __ATOMIC_RELAXED,
                           __HIP_MEMORY_SCOPE_AGENT);
        f32x4 ov = { hv[0], hv[1], hv[2], hv[3] };
        store_wt16(out + ((size_t)bg * T_STEPS + t) * M_SZ + m0, ov);
        if (k == T_STEPS) {
          f32x4 hf = { hv[0], hv[1], hv[2], hv[3] };
          f32x4 cf = { c_st[0], c_st[1], c_st[2], c_st[3] };
          store_wt16(out + OUTS + (size_t)BM + (size_t)bg * M_SZ + m0, hf);
          store_wt16(out + OUTS + 3 * (size_t)BM + (size_t)bg * M_SZ + m0, cf);
        }
      }
    }

    // ---- grid barrier: 32-leaf tree + per-XCD broadcast release ----
    if (k < T_STEPS) {
      const int target = k + 1;
      const bool invstep = ((k & (RING - 1)) == (RING - 1));
      // h producers drain their h store; out-store (HBM) may keep flying (vmcnt(1))
      if (w < 4)
        asm volatile("s_waitcnt vmcnt(0)" ::: "memory");
      else if (w >= 8 && w < 12)
        asm volatile("s_waitcnt vmcnt(1)" ::: "memory");
      __builtin_amdgcn_s_barrier();          // all h stores visible at LLC
      if (tid == 0) {
        int* leaf = bar + 16 * (cu & 31);    // 8 WGs per leaf
        int* root = bar + 16 * 32;
        int prev = __hip_atomic_fetch_add(leaf, 1, __ATOMIC_RELAXED, __HIP_MEMORY_SCOPE_AGENT);
        if ((prev & 7) == 7) {
          int pr2 = __hip_atomic_fetch_add(root, 1, __ATOMIC_RELAXED, __HIP_MEMORY_SCOPE_AGENT);
          if ((pr2 & 31) == 31) {
            // LAST ARRIVER: broadcast release to all 8 XCD lines
#pragma unroll
            for (int xx = 0; xx < 8; ++xx)
              __hip_atomic_store(bar + 16 * (34 + xx), target, __ATOMIC_RELAXED,
                                 __HIP_MEMORY_SCOPE_AGENT);
          }
        }
        int guard = 0;
        int* rel  = bar + 16 * (34 + xcd);
        int* relB = bar + 16 * (42 + xcd);
        if (!invstep) {
          while (__hip_atomic_load(rel, __ATOMIC_RELAXED, __HIP_MEMORY_SCOPE_AGENT) < target) {
            __builtin_amdgcn_s_sleep(1);
            if (++guard > (1 << 20)) break;  // failsafe: wrong answer, not hang
          }
        } else if (leader) {
          while (__hip_atomic_load(rel, __ATOMIC_RELAXED, __HIP_MEMORY_SCOPE_AGENT) < target) {
            __builtin_amdgcn_s_sleep(1);
            if (++guard > (1 << 20)) break;
          }
          asm volatile("buffer_inv sc0 sc1\n\ts_waitcnt vmcnt(0)" ::: "memory");
          __hip_atomic_store(relB, target, __ATOMIC_RELAXED, __HIP_MEMORY_SCOPE_AGENT);
        } else {
          while (__hip_atomic_load(relB, __ATOMIC_RELAXED, __HIP_MEMORY_SCOPE_AGENT) < target) {
            __builtin_amdgcn_s_sleep(1);
            if (++guard > (1 << 20)) break;
          }
          asm volatile("buffer_inv sc0\n\ts_waitcnt vmcnt(0)" ::: "memory");  // L1 only
        }
      }
      __builtin_amdgcn_s_barrier();          // release within WG
      __builtin_amdgcn_sched_barrier(0);     // keep next-step h loads below
    }
  }
}

extern "C" void kernel_launch(void* const* d_in, const int* in_sizes, int n_in,
                              void* d_out, int out_size, void* d_ws, size_t ws_size,
                              hipStream_t stream) {
  (void)in_sizes; (void)n_in; (void)out_size; (void)ws_size;
  const float* x  = (const float*)d_in[0];
  const float* h  = (const float*)d_in[1];
  const float* c  = (const float*)d_in[2];
  const float* Wx = (const float*)d_in[3];
  const float* Wh = (const float*)d_in[4];
  const float* b  = (const float*)d_in[5];
  float* out = (float*)d_out;

  char* ws = (char*)d_ws;
  int* bar = (int*)ws;                              // counter cachelines
  unsigned short* h0r = (unsigned short*)(ws + 4096);
  unsigned short* h1r = (unsigned short*)(ws + 4096 + (size_t)RING * BM * 2);
  unsigned short* xb  = (unsigned short*)(ws + 4096 + (size_t)RING * BM * 4);
  // ws use: 4096 + 2*4MB (h rings) + 32MB (xb) ~= 40 MB

  (void)hipMemsetAsync(ws, 0, 4096, stream);
  convert_x_kernel<<<2048, 256, 0, stream>>>(x, xb, (B_SZ * T_STEPS * N_SZ) / 4);
  init_h_kernel<<<256, 256, 0, stream>>>(h, h0r, h1r);
  lstm_persistent<<<256, 1024, 0, stream>>>(xb, c, Wx, Wh, b, out, h0r, h1r, bar);
}